// Round 3
// baseline (283.896 us; speedup 1.0000x reference)
//
#include <hip/hip_runtime.h>

// Problem constants (fixed by setup_inputs): N=2048, d=256, T=256, Q=64
#define NN   2048
#define DD   256
#define TT   256
#define NYC  16384           // T*Q flattened y columns
#define CHUNK_COLS 128
#define NCHUNK_XY 128        // 16384 / 128 cols per chunk
#define NCHUNK_XX 16         // 2048 / 128

static constexpr float INV_TEMP = 1.0f / 0.3f;

typedef __bf16 bf16x8 __attribute__((ext_vector_type(8)));
typedef float  f32x4  __attribute__((ext_vector_type(4)));

// Frag-linear layout: for a matrix M[C][256] (bf16), fragment index
// j = (g*8 + ks)*64 + lane holds M[g*16 + (lane&15)][ks*32 + (lane>>4)*8 .. +7].
// Every wave MFMA operand load is a contiguous 1 KB global read; the SAME
// layout serves both A and B of mfma_f32_16x16x32_bf16.

// ------------------------------------------------ convert + zero accumulators
// 4 consecutive threads cover the 4 k-quads of ONE column -> 128 B-contiguous
// reads per thread-quad; frag-linear write is a dense in-wave permutation of a
// 1 KB block (coalesced at line granularity).
__global__ void cvt_zero_kernel(const float* __restrict__ x, const float* __restrict__ y,
                                bf16x8* __restrict__ xfl, bf16x8* __restrict__ yfl,
                                float* __restrict__ acc /* 3*NN floats: Tot,Pxy,Pxx */) {
    const int tid0   = blockIdx.x * blockDim.x + threadIdx.x;
    const int stride = gridDim.x * blockDim.x;
    for (int j = tid0; j < 3 * NN; j += stride) acc[j] = 0.f;

    const int NXF = NN * DD / 8;          // 65536 x-fragments
    for (int j = tid0; j < NXF; j += stride) {
        const int gk  = j >> 6;           // g*8 + ks
        const int sub = j & 63;
        const int qq  = sub & 3;          // k-quad (lane>>4 in fragment space)
        const int cc  = (sub >> 2) & 15;  // col-within-16 (lane&15)
        const int col = ((gk >> 3) << 4) + cc;
        const int k0  = ((gk & 7) << 5) + (qq << 3);
        const float4* s = (const float4*)(x + (size_t)col * DD + k0);
        float4 v0 = s[0], v1 = s[1];
        bf16x8 o;
        o[0] = (__bf16)v0.x; o[1] = (__bf16)v0.y; o[2] = (__bf16)v0.z; o[3] = (__bf16)v0.w;
        o[4] = (__bf16)v1.x; o[5] = (__bf16)v1.y; o[6] = (__bf16)v1.z; o[7] = (__bf16)v1.w;
        xfl[(size_t)gk * 64 + qq * 16 + cc] = o;
    }
    const int NYF = NYC * DD / 8;         // 524288 y-fragments
    for (int j = tid0; j < NYF; j += stride) {
        const int gk  = j >> 6;
        const int sub = j & 63;
        const int qq  = sub & 3;
        const int cc  = (sub >> 2) & 15;
        const int col = ((gk >> 3) << 4) + cc;
        const int k0  = ((gk & 7) << 5) + (qq << 3);
        const float4* s = (const float4*)(y + (size_t)col * DD + k0);
        float4 v0 = s[0], v1 = s[1];
        bf16x8 o;
        o[0] = (__bf16)v0.x; o[1] = (__bf16)v0.y; o[2] = (__bf16)v0.z; o[3] = (__bf16)v0.w;
        o[4] = (__bf16)v1.x; o[5] = (__bf16)v1.y; o[6] = (__bf16)v1.z; o[7] = (__bf16)v1.w;
        yfl[(size_t)gk * 64 + qq * 16 + cc] = o;
    }
}

// ------------------------------------------------ stats (GEMM + exp + grouped sums)
// 1152 blocks (XCD-swizzled): (bx row-block of 256 rows, chunk of 128 cols;
// chunks 0..127 = x@y^T, 128..143 = x@x^T). 4 waves/block, each wave owns
// 64 rows; A panel (64x256) in registers. No LDS, no barriers.
// R2 counters: occupancy 12% (1 wave/SIMD) was the wall -> halved CHUNK_COLS
// doubles block supply; VGPR=124 <= 128 so 4 blocks/CU resident = 4 waves/SIMD.
__global__ __launch_bounds__(256, 4) void stats_kernel(
        const bf16x8* __restrict__ xfl, const bf16x8* __restrict__ yfl,
        const int* __restrict__ tid,
        float* __restrict__ Tot, float* __restrict__ Pxy,
        float* __restrict__ Pxx, float* __restrict__ diag) {
    const int id    = blockIdx.x;
    // XCD swizzle: the 8 row-blocks of a chunk land on the same XCD (id%8 const).
    const int chunk = (id & 7) + ((id >> 6) << 3);   // 0..143
    const int bx    = (id >> 3) & 7;                 // 0..7
    const int mode  = (chunk >= NCHUNK_XY);          // 0 = x@y^T, 1 = x@x^T
    const int colbase = (mode ? chunk - NCHUNK_XY : chunk) * CHUNK_COLS;
    const bf16x8* __restrict__ colfl = mode ? xfl : yfl;

    const int lane = threadIdx.x & 63;
    const int w    = threadIdx.x >> 6;
    const int c16  = lane & 15;
    const int q    = lane >> 4;
    const int rowbase = bx * 256 + w * 64;
    const int rowg    = rowbase >> 4;                // row16-group index

    // A fragments: 64 rows x K=256 resident in registers (128 VGPRs).
    bf16x8 a[4][8];
#pragma unroll
    for (int t = 0; t < 4; t++)
#pragma unroll
        for (int ks = 0; ks < 8; ks++)
            a[t][ks] = xfl[((size_t)(rowg + t) * 8 + ks) * 64 + lane];

    // Row track-ids packed 4x8-bit (tids < 256) to save VGPRs.
    int trow[4];
#pragma unroll
    for (int t = 0; t < 4; t++) {
        const int rb = rowbase + t * 16 + q * 4;
        trow[t] = tid[rb] | (tid[rb + 1] << 8) | (tid[rb + 2] << 16) | (tid[rb + 3] << 24);
    }

    const bf16x8* bptr = colfl + (size_t)(colbase >> 4) * 8 * 64 + lane;
    const bool wantdiag = mode && (bx == (colbase >> 8));

    float tot[4][4] = {};
    float pos[4][4] = {};

    bf16x8 b0[4], b1[4];
#pragma unroll
    for (int s = 0; s < 4; s++) b0[s] = bptr[(size_t)s * 64];

    for (int ct = 0; ct < CHUNK_COLS / 16; ct++) {
        // prefetch second half of this group while first half computes
#pragma unroll
        for (int s = 0; s < 4; s++) b1[s] = bptr[((size_t)ct * 8 + 4 + s) * 64];
        const int col    = colbase + ct * 16 + c16;
        const int coltid = mode ? tid[col] : (col & (TT - 1));

        f32x4 acc[4];
#pragma unroll
        for (int t = 0; t < 4; t++) acc[t] = (f32x4){0.f, 0.f, 0.f, 0.f};

#pragma unroll
        for (int s = 0; s < 4; s++)
#pragma unroll
            for (int t = 0; t < 4; t++)
                acc[t] = __builtin_amdgcn_mfma_f32_16x16x32_bf16(a[t][s], b0[s], acc[t], 0, 0, 0);

        if (ct < CHUNK_COLS / 16 - 1) {  // prefetch next group's first half
#pragma unroll
            for (int s = 0; s < 4; s++) b0[s] = bptr[((size_t)(ct + 1) * 8 + s) * 64];
        }

#pragma unroll
        for (int s = 0; s < 4; s++)
#pragma unroll
            for (int t = 0; t < 4; t++)
                acc[t] = __builtin_amdgcn_mfma_f32_16x16x32_bf16(a[t][4 + s], b1[s], acc[t], 0, 0, 0);

        // epilogue: exp + grouped accumulation (overlaps next b0 loads)
#pragma unroll
        for (int t = 0; t < 4; t++) {
            const int rw0 = rowbase + t * 16 + q * 4;
#pragma unroll
            for (int r = 0; r < 4; r++) {
                const float val = __expf(acc[t][r] * INV_TEMP);
                tot[t][r] += val;
                pos[t][r] += (((trow[t] >> (8 * r)) & 255) == coltid) ? val : 0.f;
                if (wantdiag && col == rw0 + r)
                    diag[col] = val;                 // unique writer per diagonal elem
            }
        }
    }

    // Reduce across the 16 column-lanes sharing (q, r); one atomic per row.
#pragma unroll
    for (int t = 0; t < 4; t++)
#pragma unroll
        for (int r = 0; r < 4; r++) {
            float aS = tot[t][r], p = pos[t][r];
#pragma unroll
            for (int off = 1; off < 16; off <<= 1) {
                aS += __shfl_xor(aS, off);
                p  += __shfl_xor(p, off);
            }
            if (c16 == 0) {
                const int row = rowbase + t * 16 + q * 4 + r;
                atomicAdd(&Tot[row], aS);
                atomicAdd(mode ? &Pxx[row] : &Pxy[row], p);
            }
        }
}

// ------------------------------------------------ finalize (reads 32 KB only)
__global__ void finalize_kernel(const float* __restrict__ Tot, const float* __restrict__ Pxy,
                                const float* __restrict__ Pxx, const float* __restrict__ diag,
                                const int* __restrict__ tid, float* __restrict__ out) {
    __shared__ float num_s[TT], den_s[TT];
    __shared__ int cnt_s[TT];
    const int t = threadIdx.x;  // 256 threads
    num_s[t] = 0.f; den_s[t] = 0.f; cnt_s[t] = 0;
    __syncthreads();
    for (int i = t; i < NN; i += 256) {
        float tt_ = Tot[i], pxy = Pxy[i], pxx = Pxx[i];
        float num = pxy + 0.5f * (pxx - diag[i]);
        float den = tt_ - pxy - pxx;
        int tr = tid[i];
        atomicAdd(&num_s[tr], num);
        atomicAdd(&den_s[tr], den);
        atomicAdd(&cnt_s[tr], 1);
    }
    __syncthreads();
    float lt = 0.f, pr = 0.f;
    if (cnt_s[t] > 0) {
        lt = -logf(num_s[t] / (den_s[t] + num_s[t]));
        pr = 1.f;
    }
    for (int off = 32; off; off >>= 1) { lt += __shfl_down(lt, off); pr += __shfl_down(pr, off); }
    __shared__ float ls[4], ps[4];
    if ((t & 63) == 0) { ls[t >> 6] = lt; ps[t >> 6] = pr; }
    __syncthreads();
    if (t == 0) out[0] = (ls[0] + ls[1] + ls[2] + ls[3]) / (ps[0] + ps[1] + ps[2] + ps[3]);
}

// ------------------------------------------------ launch
extern "C" void kernel_launch(void* const* d_in, const int* in_sizes, int n_in,
                              void* d_out, int out_size, void* d_ws, size_t ws_size,
                              hipStream_t stream) {
    const float* x   = (const float*)d_in[0];
    const int*   tid = (const int*)d_in[1];
    const float* y   = (const float*)d_in[2];
    float* out = (float*)d_out;

    char* ws = (char*)d_ws;
    bf16x8* xfl = (bf16x8*)ws;                       // 1 MB frag-linear x
    bf16x8* yfl = (bf16x8*)(ws + (1u << 20));        // 8 MB frag-linear y
    float* acc  = (float*)(ws + 9u * (1u << 20));    // Tot,Pxy,Pxx,diag: 4*2048 f32
    float* Tot  = acc;
    float* Pxy  = acc + NN;
    float* Pxx  = acc + 2 * NN;
    float* diag = acc + 3 * NN;                      // fully rewritten by stats (mode 1)

    cvt_zero_kernel<<<2304, 256, 0, stream>>>(x, y, xfl, yfl, acc);
    stats_kernel<<<8 * (NCHUNK_XY + NCHUNK_XX), 256, 0, stream>>>(
        xfl, yfl, tid, Tot, Pxy, Pxx, diag);
    finalize_kernel<<<1, 256, 0, stream>>>(Tot, Pxy, Pxx, diag, tid, out);
}

// Round 6
// 120.173 us; speedup vs baseline: 2.3624x; 2.3624x over previous
//
#include <hip/hip_runtime.h>

// Problem constants (fixed by setup_inputs): N=2048, d=256, T=256, Q=64
#define NN   2048
#define DD   256
#define TT   256
#define NYC  16384           // T*Q flattened y columns
#define CHUNK_COLS 128
#define NCHUNK_XY 128        // 16384 / 128 cols per chunk
#define NCHUNK_XX 16         // 2048 / 128
#define NROWBLK   16         // 2048 / 128 rows per block

static constexpr float INV_TEMP = 1.0f / 0.3f;

typedef __bf16 bf16x8 __attribute__((ext_vector_type(8)));
typedef float  f32x4  __attribute__((ext_vector_type(4)));

// Frag-linear layout: for a matrix M[C][256] (bf16), fragment index
// j = (g*8 + ks)*64 + lane holds M[g*16 + (lane&15)][ks*32 + (lane>>4)*8 .. +7].
// Every wave MFMA operand load is a contiguous 1 KB global read; the SAME
// layout serves both A and B of mfma_f32_16x16x32_bf16.

// ------------------------------------------------ convert + zero accumulators
__global__ void cvt_zero_kernel(const float* __restrict__ x, const float* __restrict__ y,
                                bf16x8* __restrict__ xfl, bf16x8* __restrict__ yfl,
                                float* __restrict__ acc /* 3*NN floats: Tot,Pxy,Pxx */) {
    const int tid0   = blockIdx.x * blockDim.x + threadIdx.x;
    const int stride = gridDim.x * blockDim.x;
    for (int j = tid0; j < 3 * NN; j += stride) acc[j] = 0.f;

    const int NXF = NN * DD / 8;          // 65536 x-fragments
    for (int j = tid0; j < NXF; j += stride) {
        const int gk  = j >> 6;           // g*8 + ks
        const int sub = j & 63;
        const int qq  = sub & 3;          // k-quad (lane>>4 in fragment space)
        const int cc  = (sub >> 2) & 15;  // col-within-16 (lane&15)
        const int col = ((gk >> 3) << 4) + cc;
        const int k0  = ((gk & 7) << 5) + (qq << 3);
        const float4* s = (const float4*)(x + (size_t)col * DD + k0);
        float4 v0 = s[0], v1 = s[1];
        bf16x8 o;
        o[0] = (__bf16)v0.x; o[1] = (__bf16)v0.y; o[2] = (__bf16)v0.z; o[3] = (__bf16)v0.w;
        o[4] = (__bf16)v1.x; o[5] = (__bf16)v1.y; o[6] = (__bf16)v1.z; o[7] = (__bf16)v1.w;
        xfl[(size_t)gk * 64 + qq * 16 + cc] = o;
    }
    const int NYF = NYC * DD / 8;         // 524288 y-fragments
    for (int j = tid0; j < NYF; j += stride) {
        const int gk  = j >> 6;
        const int sub = j & 63;
        const int qq  = sub & 3;
        const int cc  = (sub >> 2) & 15;
        const int col = ((gk >> 3) << 4) + cc;
        const int k0  = ((gk & 7) << 5) + (qq << 3);
        const float4* s = (const float4*)(y + (size_t)col * DD + k0);
        float4 v0 = s[0], v1 = s[1];
        bf16x8 o;
        o[0] = (__bf16)v0.x; o[1] = (__bf16)v0.y; o[2] = (__bf16)v0.z; o[3] = (__bf16)v0.w;
        o[4] = (__bf16)v1.x; o[5] = (__bf16)v1.y; o[6] = (__bf16)v1.z; o[7] = (__bf16)v1.w;
        yfl[(size_t)gk * 64 + qq * 16 + cc] = o;
    }
}

// ------------------------------------------------ stats (GEMM + exp + grouped sums)
// 2304 blocks (XCD-swizzled): (bx row-block of 128 rows, chunk of 128 cols;
// chunks 0..127 = x@y^T, 128..143 = x@x^T). 4 waves/block, each wave owns
// 32 rows (t=2). No LDS, no barriers.
// R3 lesson: bf16x8 = 4 VGPRs, so t=4's A panel alone is 128 regs (total ~250
// -> 2 waves/SIMD; capping at 128 spilled 600 MB of scratch). t=2 halves the
// footprint (~145 regs) so 3 waves/SIMD fit HONESTLY under launch_bounds(256,3).
__global__ __launch_bounds__(256, 3) void stats_kernel(
        const bf16x8* __restrict__ xfl, const bf16x8* __restrict__ yfl,
        const int* __restrict__ tid,
        float* __restrict__ Tot, float* __restrict__ Pxy,
        float* __restrict__ Pxx, float* __restrict__ diag) {
    const int id    = blockIdx.x;
    // XCD swizzle: id = hi*128 + bx*8 + lo; lo = XCD, chunk = lo + 8*hi.
    const int chunk = (id & 7) + ((id >> 7) << 3);   // 0..143
    const int bx    = (id >> 3) & 15;                // 0..15 row-block
    const int mode  = (chunk >= NCHUNK_XY);          // 0 = x@y^T, 1 = x@x^T
    const int colbase = (mode ? chunk - NCHUNK_XY : chunk) * CHUNK_COLS;
    const bf16x8* __restrict__ colfl = mode ? xfl : yfl;

    const int lane = threadIdx.x & 63;
    const int w    = threadIdx.x >> 6;
    const int c16  = lane & 15;
    const int q    = lane >> 4;
    const int rowbase = bx * 128 + w * 32;
    const int rowg    = rowbase >> 4;                // row16-group index

    // A fragments: 32 rows x K=256 resident in registers (64 VGPRs).
    bf16x8 a[2][8];
#pragma unroll
    for (int t = 0; t < 2; t++)
#pragma unroll
        for (int ks = 0; ks < 8; ks++)
            a[t][ks] = xfl[((size_t)(rowg + t) * 8 + ks) * 64 + lane];

    // Row track-ids packed 4x8-bit (tids < 256).
    int trow[2];
#pragma unroll
    for (int t = 0; t < 2; t++) {
        const int rb = rowbase + t * 16 + q * 4;
        trow[t] = tid[rb] | (tid[rb + 1] << 8) | (tid[rb + 2] << 16) | (tid[rb + 3] << 24);
    }

    const bf16x8* bptr = colfl + (size_t)(colbase >> 4) * 8 * 64 + lane;
    const bool wantdiag = mode && (bx == (colbase >> 7));

    float tot[2][4] = {};
    float pos[2][4] = {};

    bf16x8 b0[4], b1[4];
#pragma unroll
    for (int s = 0; s < 4; s++) b0[s] = bptr[(size_t)s * 64];

    for (int ct = 0; ct < CHUNK_COLS / 16; ct++) {
        // prefetch second half of this group while first half computes
#pragma unroll
        for (int s = 0; s < 4; s++) b1[s] = bptr[((size_t)ct * 8 + 4 + s) * 64];
        const int col    = colbase + ct * 16 + c16;
        const int coltid = mode ? tid[col] : (col & (TT - 1));

        f32x4 acc[2];
#pragma unroll
        for (int t = 0; t < 2; t++) acc[t] = (f32x4){0.f, 0.f, 0.f, 0.f};

#pragma unroll
        for (int s = 0; s < 4; s++)
#pragma unroll
            for (int t = 0; t < 2; t++)
                acc[t] = __builtin_amdgcn_mfma_f32_16x16x32_bf16(a[t][s], b0[s], acc[t], 0, 0, 0);

        if (ct < CHUNK_COLS / 16 - 1) {  // prefetch next group's first half
#pragma unroll
            for (int s = 0; s < 4; s++) b0[s] = bptr[((size_t)(ct + 1) * 8 + s) * 64];
        }

#pragma unroll
        for (int s = 0; s < 4; s++)
#pragma unroll
            for (int t = 0; t < 2; t++)
                acc[t] = __builtin_amdgcn_mfma_f32_16x16x32_bf16(a[t][4 + s], b1[s], acc[t], 0, 0, 0);

        // epilogue: exp + grouped accumulation (overlaps next b0 loads)
#pragma unroll
        for (int t = 0; t < 2; t++) {
            const int rw0 = rowbase + t * 16 + q * 4;
#pragma unroll
            for (int r = 0; r < 4; r++) {
                const float val = __expf(acc[t][r] * INV_TEMP);
                tot[t][r] += val;
                pos[t][r] += (((trow[t] >> (8 * r)) & 255) == coltid) ? val : 0.f;
                if (wantdiag && col == rw0 + r)
                    diag[col] = val;                 // unique writer per diagonal elem
            }
        }
    }

    // Reduce across the 16 column-lanes sharing (q, r); one atomic per row.
#pragma unroll
    for (int t = 0; t < 2; t++)
#pragma unroll
        for (int r = 0; r < 4; r++) {
            float aS = tot[t][r], p = pos[t][r];
#pragma unroll
            for (int off = 1; off < 16; off <<= 1) {
                aS += __shfl_xor(aS, off);
                p  += __shfl_xor(p, off);
            }
            if (c16 == 0) {
                const int row = rowbase + t * 16 + q * 4 + r;
                atomicAdd(&Tot[row], aS);
                atomicAdd(mode ? &Pxx[row] : &Pxy[row], p);
            }
        }
}

// ------------------------------------------------ finalize (reads 32 KB only)
__global__ void finalize_kernel(const float* __restrict__ Tot, const float* __restrict__ Pxy,
                                const float* __restrict__ Pxx, const float* __restrict__ diag,
                                const int* __restrict__ tid, float* __restrict__ out) {
    __shared__ float num_s[TT], den_s[TT];
    __shared__ int cnt_s[TT];
    const int t = threadIdx.x;  // 256 threads
    num_s[t] = 0.f; den_s[t] = 0.f; cnt_s[t] = 0;
    __syncthreads();
    for (int i = t; i < NN; i += 256) {
        float tt_ = Tot[i], pxy = Pxy[i], pxx = Pxx[i];
        float num = pxy + 0.5f * (pxx - diag[i]);
        float den = tt_ - pxy - pxx;
        int tr = tid[i];
        atomicAdd(&num_s[tr], num);
        atomicAdd(&den_s[tr], den);
        atomicAdd(&cnt_s[tr], 1);
    }
    __syncthreads();
    float lt = 0.f, pr = 0.f;
    if (cnt_s[t] > 0) {
        lt = -logf(num_s[t] / (den_s[t] + num_s[t]));
        pr = 1.f;
    }
    for (int off = 32; off; off >>= 1) { lt += __shfl_down(lt, off); pr += __shfl_down(pr, off); }
    __shared__ float ls[4], ps[4];
    if ((t & 63) == 0) { ls[t >> 6] = lt; ps[t >> 6] = pr; }
    __syncthreads();
    if (t == 0) out[0] = (ls[0] + ls[1] + ls[2] + ls[3]) / (ps[0] + ps[1] + ps[2] + ps[3]);
}

// ------------------------------------------------ launch
extern "C" void kernel_launch(void* const* d_in, const int* in_sizes, int n_in,
                              void* d_out, int out_size, void* d_ws, size_t ws_size,
                              hipStream_t stream) {
    const float* x   = (const float*)d_in[0];
    const int*   tid = (const int*)d_in[1];
    const float* y   = (const float*)d_in[2];
    float* out = (float*)d_out;

    char* ws = (char*)d_ws;
    bf16x8* xfl = (bf16x8*)ws;                       // 1 MB frag-linear x
    bf16x8* yfl = (bf16x8*)(ws + (1u << 20));        // 8 MB frag-linear y
    float* acc  = (float*)(ws + 9u * (1u << 20));    // Tot,Pxy,Pxx,diag: 4*2048 f32
    float* Tot  = acc;
    float* Pxy  = acc + NN;
    float* Pxx  = acc + 2 * NN;
    float* diag = acc + 3 * NN;                      // fully rewritten by stats (mode 1)

    cvt_zero_kernel<<<2304, 256, 0, stream>>>(x, y, xfl, yfl, acc);
    stats_kernel<<<NROWBLK * (NCHUNK_XY + NCHUNK_XX), 256, 0, stream>>>(
        xfl, yfl, tid, Tot, Pxy, Pxx, diag);
    finalize_kernel<<<1, 256, 0, stream>>>(Tot, Pxy, Pxx, diag, tid, out);
}

// Round 11
// 114.211 us; speedup vs baseline: 2.4857x; 1.0522x over previous
//
#include <hip/hip_runtime.h>

// Problem constants (fixed by setup_inputs): N=2048, d=256, T=256, Q=64
#define NN   2048
#define DD   256
#define TT   256
#define NYC  16384           // T*Q flattened y columns
#define CHUNK_COLS 128
#define NCHUNK_XY 128        // 16384 / 128 cols per chunk
#define NCHUNK_XX 16         // 2048 / 128
#define NROWBLK   16         // 2048 / 128 rows per block

static constexpr float INV_TEMP = 1.0f / 0.3f;

typedef __bf16 bf16x8 __attribute__((ext_vector_type(8)));
typedef float  f32x4  __attribute__((ext_vector_type(4)));

// Frag-linear layout: for a matrix M[C][256] (bf16), fragment index
// j = (g*8 + ks)*64 + lane holds M[g*16 + (lane&15)][ks*32 + (lane>>4)*8 .. +7].
// Every wave MFMA operand load is a contiguous 1 KB global read; the SAME
// layout serves both A and B of mfma_f32_16x16x32_bf16.

// ------------------------------------------------ convert + zero accumulators
__global__ void cvt_zero_kernel(const float* __restrict__ x, const float* __restrict__ y,
                                bf16x8* __restrict__ xfl, bf16x8* __restrict__ yfl,
                                float* __restrict__ acc /* 3*NN floats: Tot,Pxy,Pxx */) {
    const int tid0   = blockIdx.x * blockDim.x + threadIdx.x;
    const int stride = gridDim.x * blockDim.x;
    for (int j = tid0; j < 3 * NN; j += stride) acc[j] = 0.f;

    const int NXF = NN * DD / 8;          // 65536 x-fragments
    for (int j = tid0; j < NXF; j += stride) {
        const int gk  = j >> 6;           // g*8 + ks
        const int sub = j & 63;
        const int qq  = sub & 3;          // k-quad (lane>>4 in fragment space)
        const int cc  = (sub >> 2) & 15;  // col-within-16 (lane&15)
        const int col = ((gk >> 3) << 4) + cc;
        const int k0  = ((gk & 7) << 5) + (qq << 3);
        const float4* s = (const float4*)(x + (size_t)col * DD + k0);
        float4 v0 = s[0], v1 = s[1];
        bf16x8 o;
        o[0] = (__bf16)v0.x; o[1] = (__bf16)v0.y; o[2] = (__bf16)v0.z; o[3] = (__bf16)v0.w;
        o[4] = (__bf16)v1.x; o[5] = (__bf16)v1.y; o[6] = (__bf16)v1.z; o[7] = (__bf16)v1.w;
        xfl[(size_t)gk * 64 + qq * 16 + cc] = o;
    }
    const int NYF = NYC * DD / 8;         // 524288 y-fragments
    for (int j = tid0; j < NYF; j += stride) {
        const int gk  = j >> 6;
        const int sub = j & 63;
        const int qq  = sub & 3;
        const int cc  = (sub >> 2) & 15;
        const int col = ((gk >> 3) << 4) + cc;
        const int k0  = ((gk & 7) << 5) + (qq << 3);
        const float4* s = (const float4*)(y + (size_t)col * DD + k0);
        float4 v0 = s[0], v1 = s[1];
        bf16x8 o;
        o[0] = (__bf16)v0.x; o[1] = (__bf16)v0.y; o[2] = (__bf16)v0.z; o[3] = (__bf16)v0.w;
        o[4] = (__bf16)v1.x; o[5] = (__bf16)v1.y; o[6] = (__bf16)v1.z; o[7] = (__bf16)v1.w;
        yfl[(size_t)gk * 64 + qq * 16 + cc] = o;
    }
}

// ------------------------------------------------ stats (GEMM + exp + grouped sums)
// 2304 blocks (XCD-swizzled). 4 waves/block, each wave owns 32 rows (t=2),
// 128-col chunk = 8 col-tiles of 16. No LDS, no barriers.
// R6 lesson: launch_bounds(256,3) cap=168 < ~190 true need -> spilled 53 MB
// (WRITE_SIZE) and serialized on scratch reloads; per-tile time ~3300 cyc in
// BOTH R2 and R6 => fixed per-tile latency chain, not BW. This version:
//  - launch_bounds(256,2): cap 256, ZERO spill (the non-negotiable).
//  - full-tile ping-pong prefetch (bA/bB, 8 frags each, fully unrolled static
//    indices): load->use distance = 16 MFMAs + epilogue, so counted vmcnt can
//    hide the ~300-600cyc L2 latency even at 2 waves/SIMD.
//  - col-tids hoisted to prologue (gather off the critical path).
__global__ __launch_bounds__(256, 2) void stats_kernel(
        const bf16x8* __restrict__ xfl, const bf16x8* __restrict__ yfl,
        const int* __restrict__ tid,
        float* __restrict__ Tot, float* __restrict__ Pxy,
        float* __restrict__ Pxx, float* __restrict__ diag) {
    const int id    = blockIdx.x;
    // XCD swizzle: id = hi*128 + bx*8 + lo; lo = XCD, chunk = lo + 8*hi.
    const int chunk = (id & 7) + ((id >> 7) << 3);   // 0..143
    const int bx    = (id >> 3) & 15;                // 0..15 row-block
    const int mode  = (chunk >= NCHUNK_XY);          // 0 = x@y^T, 1 = x@x^T
    const int colbase = (mode ? chunk - NCHUNK_XY : chunk) * CHUNK_COLS;
    const bf16x8* __restrict__ colfl = mode ? xfl : yfl;

    const int lane = threadIdx.x & 63;
    const int w    = threadIdx.x >> 6;
    const int c16  = lane & 15;
    const int q    = lane >> 4;
    const int rowbase = bx * 128 + w * 32;
    const int rowg    = rowbase >> 4;                // row16-group index

    // A fragments: 32 rows x K=256 resident in registers (64 VGPRs).
    bf16x8 a[2][8];
#pragma unroll
    for (int t = 0; t < 2; t++)
#pragma unroll
        for (int ks = 0; ks < 8; ks++)
            a[t][ks] = xfl[((size_t)(rowg + t) * 8 + ks) * 64 + lane];

    // Row track-ids packed 4x8-bit (tids < 256).
    int trow[2];
#pragma unroll
    for (int t = 0; t < 2; t++) {
        const int rb = rowbase + t * 16 + q * 4;
        trow[t] = tid[rb] | (tid[rb + 1] << 8) | (tid[rb + 2] << 16) | (tid[rb + 3] << 24);
    }

    // Column track-ids for all 8 tiles, hoisted (static-indexed under unroll).
    int ctid[8];
#pragma unroll
    for (int ct = 0; ct < 8; ct++) {
        const int col = colbase + ct * 16 + c16;
        ctid[ct] = mode ? tid[col] : (col & (TT - 1));
    }

    const bf16x8* bptr = colfl + (size_t)(colbase >> 4) * 8 * 64 + lane;
    const bool wantdiag = mode && (bx == (colbase >> 7));

    float tot[2][4] = {};
    float pos[2][4] = {};

    bf16x8 bA[8], bB[8];
#pragma unroll
    for (int s = 0; s < 8; s++) bA[s] = bptr[(size_t)s * 64];

#pragma unroll
    for (int cp = 0; cp < 4; cp++) {
        // ---------------- even tile ct = 2*cp (data in bA; prefetch into bB)
        {
            const int ct = 2 * cp;
#pragma unroll
            for (int s = 0; s < 8; s++) bB[s] = bptr[((size_t)(ct + 1) * 8 + s) * 64];
            f32x4 acc0 = {0.f, 0.f, 0.f, 0.f};
            f32x4 acc1 = {0.f, 0.f, 0.f, 0.f};
#pragma unroll
            for (int s = 0; s < 8; s++) {
                acc0 = __builtin_amdgcn_mfma_f32_16x16x32_bf16(a[0][s], bA[s], acc0, 0, 0, 0);
                acc1 = __builtin_amdgcn_mfma_f32_16x16x32_bf16(a[1][s], bA[s], acc1, 0, 0, 0);
            }
            const int col = colbase + ct * 16 + c16;
#pragma unroll
            for (int t = 0; t < 2; t++) {
                const f32x4 acv = t ? acc1 : acc0;
                const int rw0 = rowbase + t * 16 + q * 4;
#pragma unroll
                for (int r = 0; r < 4; r++) {
                    const float val = __expf(acv[r] * INV_TEMP);
                    tot[t][r] += val;
                    pos[t][r] += (((trow[t] >> (8 * r)) & 255) == ctid[ct]) ? val : 0.f;
                    if (wantdiag && col == rw0 + r) diag[col] = val;
                }
            }
        }
        // ---------------- odd tile ct = 2*cp+1 (data in bB; prefetch into bA)
        {
            const int ct = 2 * cp + 1;
            if (cp < 3) {
#pragma unroll
                for (int s = 0; s < 8; s++) bA[s] = bptr[((size_t)(ct + 1) * 8 + s) * 64];
            }
            f32x4 acc0 = {0.f, 0.f, 0.f, 0.f};
            f32x4 acc1 = {0.f, 0.f, 0.f, 0.f};
#pragma unroll
            for (int s = 0; s < 8; s++) {
                acc0 = __builtin_amdgcn_mfma_f32_16x16x32_bf16(a[0][s], bB[s], acc0, 0, 0, 0);
                acc1 = __builtin_amdgcn_mfma_f32_16x16x32_bf16(a[1][s], bB[s], acc1, 0, 0, 0);
            }
            const int col = colbase + ct * 16 + c16;
#pragma unroll
            for (int t = 0; t < 2; t++) {
                const f32x4 acv = t ? acc1 : acc0;
                const int rw0 = rowbase + t * 16 + q * 4;
#pragma unroll
                for (int r = 0; r < 4; r++) {
                    const float val = __expf(acv[r] * INV_TEMP);
                    tot[t][r] += val;
                    pos[t][r] += (((trow[t] >> (8 * r)) & 255) == ctid[ct]) ? val : 0.f;
                    if (wantdiag && col == rw0 + r) diag[col] = val;
                }
            }
        }
    }

    // Reduce across the 16 column-lanes sharing (q, r); one atomic per row.
#pragma unroll
    for (int t = 0; t < 2; t++)
#pragma unroll
        for (int r = 0; r < 4; r++) {
            float aS = tot[t][r], p = pos[t][r];
#pragma unroll
            for (int off = 1; off < 16; off <<= 1) {
                aS += __shfl_xor(aS, off);
                p  += __shfl_xor(p, off);
            }
            if (c16 == 0) {
                const int row = rowbase + t * 16 + q * 4 + r;
                atomicAdd(&Tot[row], aS);
                atomicAdd(mode ? &Pxx[row] : &Pxy[row], p);
            }
        }
}

// ------------------------------------------------ finalize (reads 32 KB only)
__global__ void finalize_kernel(const float* __restrict__ Tot, const float* __restrict__ Pxy,
                                const float* __restrict__ Pxx, const float* __restrict__ diag,
                                const int* __restrict__ tid, float* __restrict__ out) {
    __shared__ float num_s[TT], den_s[TT];
    __shared__ int cnt_s[TT];
    const int t = threadIdx.x;  // 256 threads
    num_s[t] = 0.f; den_s[t] = 0.f; cnt_s[t] = 0;
    __syncthreads();
    for (int i = t; i < NN; i += 256) {
        float tt_ = Tot[i], pxy = Pxy[i], pxx = Pxx[i];
        float num = pxy + 0.5f * (pxx - diag[i]);
        float den = tt_ - pxy - pxx;
        int tr = tid[i];
        atomicAdd(&num_s[tr], num);
        atomicAdd(&den_s[tr], den);
        atomicAdd(&cnt_s[tr], 1);
    }
    __syncthreads();
    float lt = 0.f, pr = 0.f;
    if (cnt_s[t] > 0) {
        lt = -logf(num_s[t] / (den_s[t] + num_s[t]));
        pr = 1.f;
    }
    for (int off = 32; off; off >>= 1) { lt += __shfl_down(lt, off); pr += __shfl_down(pr, off); }
    __shared__ float ls[4], ps[4];
    if ((t & 63) == 0) { ls[t >> 6] = lt; ps[t >> 6] = pr; }
    __syncthreads();
    if (t == 0) out[0] = (ls[0] + ls[1] + ls[2] + ls[3]) / (ps[0] + ps[1] + ps[2] + ps[3]);
}

// ------------------------------------------------ launch
extern "C" void kernel_launch(void* const* d_in, const int* in_sizes, int n_in,
                              void* d_out, int out_size, void* d_ws, size_t ws_size,
                              hipStream_t stream) {
    const float* x   = (const float*)d_in[0];
    const int*   tid = (const int*)d_in[1];
    const float* y   = (const float*)d_in[2];
    float* out = (float*)d_out;

    char* ws = (char*)d_ws;
    bf16x8* xfl = (bf16x8*)ws;                       // 1 MB frag-linear x
    bf16x8* yfl = (bf16x8*)(ws + (1u << 20));        // 8 MB frag-linear y
    float* acc  = (float*)(ws + 9u * (1u << 20));    // Tot,Pxy,Pxx,diag: 4*2048 f32
    float* Tot  = acc;
    float* Pxy  = acc + NN;
    float* Pxx  = acc + 2 * NN;
    float* diag = acc + 3 * NN;                      // fully rewritten by stats (mode 1)

    cvt_zero_kernel<<<2304, 256, 0, stream>>>(x, y, xfl, yfl, acc);
    stats_kernel<<<NROWBLK * (NCHUNK_XY + NCHUNK_XX), 256, 0, stream>>>(
        xfl, yfl, tid, Tot, Pxy, Pxx, diag);
    finalize_kernel<<<1, 256, 0, stream>>>(Tot, Pxy, Pxx, diag, tid, out);
}

// Round 12
// 113.474 us; speedup vs baseline: 2.5018x; 1.0065x over previous
//
#include <hip/hip_runtime.h>

// Problem constants (fixed by setup_inputs): N=2048, d=256, T=256, Q=64
#define NN   2048
#define DD   256
#define TT   256
#define NYC  16384           // T*Q flattened y columns
#define CHUNK_COLS 128
#define NCHUNK_XY 128        // 16384 / 128 cols per chunk
#define NCHUNK_XX 16         // 2048 / 128
#define NROWBLK   16         // 2048 / 128 rows per block

static constexpr float INV_TEMP = 1.0f / 0.3f;

typedef __bf16 bf16x8 __attribute__((ext_vector_type(8)));
typedef float  f32x4  __attribute__((ext_vector_type(4)));

// Frag-linear layout: for a matrix M[C][256] (bf16), fragment index
// j = (g*8 + ks)*64 + lane holds M[g*16 + (lane&15)][ks*32 + (lane>>4)*8 .. +7].
// A 16-col tile = 8 KB contiguous; staged to LDS it is already in ds_read
// fragment order (frag ks at lds ks*1024 + lane*16).

// ------------------------------------------------ convert + zero accumulators
__global__ void cvt_zero_kernel(const float* __restrict__ x, const float* __restrict__ y,
                                bf16x8* __restrict__ xfl, bf16x8* __restrict__ yfl,
                                float* __restrict__ acc /* 3*NN floats: Tot,Pxy,Pxx */) {
    const int tid0   = blockIdx.x * blockDim.x + threadIdx.x;
    const int stride = gridDim.x * blockDim.x;
    for (int j = tid0; j < 3 * NN; j += stride) acc[j] = 0.f;

    const int NXF = NN * DD / 8;          // 65536 x-fragments
    for (int j = tid0; j < NXF; j += stride) {
        const int gk  = j >> 6;           // g*8 + ks
        const int sub = j & 63;
        const int qq  = sub & 3;          // k-quad (lane>>4 in fragment space)
        const int cc  = (sub >> 2) & 15;  // col-within-16 (lane&15)
        const int col = ((gk >> 3) << 4) + cc;
        const int k0  = ((gk & 7) << 5) + (qq << 3);
        const float4* s = (const float4*)(x + (size_t)col * DD + k0);
        float4 v0 = s[0], v1 = s[1];
        bf16x8 o;
        o[0] = (__bf16)v0.x; o[1] = (__bf16)v0.y; o[2] = (__bf16)v0.z; o[3] = (__bf16)v0.w;
        o[4] = (__bf16)v1.x; o[5] = (__bf16)v1.y; o[6] = (__bf16)v1.z; o[7] = (__bf16)v1.w;
        xfl[(size_t)gk * 64 + qq * 16 + cc] = o;
    }
    const int NYF = NYC * DD / 8;         // 524288 y-fragments
    for (int j = tid0; j < NYF; j += stride) {
        const int gk  = j >> 6;
        const int sub = j & 63;
        const int qq  = sub & 3;
        const int cc  = (sub >> 2) & 15;
        const int col = ((gk >> 3) << 4) + cc;
        const int k0  = ((gk & 7) << 5) + (qq << 3);
        const float4* s = (const float4*)(y + (size_t)col * DD + k0);
        float4 v0 = s[0], v1 = s[1];
        bf16x8 o;
        o[0] = (__bf16)v0.x; o[1] = (__bf16)v0.y; o[2] = (__bf16)v0.z; o[3] = (__bf16)v0.w;
        o[4] = (__bf16)v1.x; o[5] = (__bf16)v1.y; o[6] = (__bf16)v1.z; o[7] = (__bf16)v1.w;
        yfl[(size_t)gk * 64 + qq * 16 + cc] = o;
    }
}

// ------------------------------------------------ stats (GEMM + exp + grouped sums)
// 2304 blocks (XCD-swizzled). 4 waves/block, each wave owns 32 rows (t=2).
// R11 lesson: harness re-poison fill = 43 us of every iteration; stats ~40 us,
// still latency-bound (1-tile-deep reg ping-pong + 2 waves/SIMD can't cover
// ~600-900 cyc cold-L2/L3 B fetch; needed depth ~4).
// This version: B staged in LDS via global_load_lds (m97 pattern), ONCE per
// block (4x less B traffic), double-buffered, 1 barrier/tile. B-VGPRs 64->16
// => ~140 total => 3 waves/SIMD honest under launch_bounds(256,3). Stage issue
// precedes the tile's ds_read+MFMA+epilogue (~500 cyc window hides the fetch).
__global__ __launch_bounds__(256, 3) void stats_kernel(
        const bf16x8* __restrict__ xfl, const bf16x8* __restrict__ yfl,
        const int* __restrict__ tid,
        float* __restrict__ Tot, float* __restrict__ Pxy,
        float* __restrict__ Pxx, float* __restrict__ diag) {
    __shared__ __align__(16) char bstage[2][8192];   // 2 x (16 cols x 256 K bf16)

    const int id    = blockIdx.x;
    // XCD swizzle: id = hi*128 + bx*8 + lo; lo = XCD, chunk = lo + 8*hi.
    const int chunk = (id & 7) + ((id >> 7) << 3);   // 0..143
    const int bx    = (id >> 3) & 15;                // 0..15 row-block
    const int mode  = (chunk >= NCHUNK_XY);          // 0 = x@y^T, 1 = x@x^T
    const int colbase = (mode ? chunk - NCHUNK_XY : chunk) * CHUNK_COLS;
    const bf16x8* __restrict__ colfl = mode ? xfl : yfl;

    const int tix  = threadIdx.x;
    const int lane = tix & 63;
    const int w    = tix >> 6;
    const int c16  = lane & 15;
    const int q    = lane >> 4;
    const int rowbase = bx * 128 + w * 32;
    const int rowg    = rowbase >> 4;                // row16-group index

    // A fragments: 32 rows x K=256 resident in registers (64 VGPRs).
    bf16x8 a[2][8];
#pragma unroll
    for (int t = 0; t < 2; t++)
#pragma unroll
        for (int ks = 0; ks < 8; ks++)
            a[t][ks] = xfl[((size_t)(rowg + t) * 8 + ks) * 64 + lane];

    // Row track-ids packed 4x8-bit (tids < 256).
    int trow[2];
#pragma unroll
    for (int t = 0; t < 2; t++) {
        const int rb = rowbase + t * 16 + q * 4;
        trow[t] = tid[rb] | (tid[rb + 1] << 8) | (tid[rb + 2] << 16) | (tid[rb + 3] << 24);
    }

    // Column track-ids for all 8 tiles (static-indexed under full unroll).
    int ctid[8];
#pragma unroll
    for (int ct = 0; ct < 8; ct++) {
        const int col = colbase + ct * 16 + c16;
        ctid[ct] = mode ? tid[col] : (col & (TT - 1));
    }

    const char* gbase = (const char*)colfl + ((size_t)(colbase >> 4)) * 8192 + tix * 16;
    const bool wantdiag = mode && (bx == (colbase >> 7));

    float tot[2][4] = {};
    float pos[2][4] = {};

    // Stage tile ct into buffer buf: 8 KB, 2 x 16 B per thread, LDS-linear.
#define STAGE(ct_, buf_)                                                              \
    do {                                                                              \
        const char* g_ = gbase + (size_t)(ct_) * 8192;                                \
        __builtin_amdgcn_global_load_lds(                                             \
            (const __attribute__((address_space(1))) void*)g_,                        \
            (__attribute__((address_space(3))) void*)&bstage[buf_][tix * 16],         \
            16, 0, 0);                                                                \
        __builtin_amdgcn_global_load_lds(                                             \
            (const __attribute__((address_space(1))) void*)(g_ + 4096),               \
            (__attribute__((address_space(3))) void*)&bstage[buf_][4096 + tix * 16],  \
            16, 0, 0);                                                                \
    } while (0)

    STAGE(0, 0);
    __syncthreads();                                  // drains vmcnt -> tile 0 ready

#pragma unroll
    for (int ct = 0; ct < 8; ct++) {
        if (ct < 7) STAGE(ct + 1, (ct + 1) & 1);      // lands under this tile's work
        const char* lbase = &bstage[ct & 1][0];

        f32x4 acc0 = {0.f, 0.f, 0.f, 0.f};
        f32x4 acc1 = {0.f, 0.f, 0.f, 0.f};
#pragma unroll
        for (int h = 0; h < 2; h++) {
            bf16x8 bf[4];
#pragma unroll
            for (int k = 0; k < 4; k++)
                bf[k] = *(const bf16x8*)(lbase + (h * 4 + k) * 1024 + lane * 16);
#pragma unroll
            for (int k = 0; k < 4; k++) {
                acc0 = __builtin_amdgcn_mfma_f32_16x16x32_bf16(a[0][h * 4 + k], bf[k], acc0, 0, 0, 0);
                acc1 = __builtin_amdgcn_mfma_f32_16x16x32_bf16(a[1][h * 4 + k], bf[k], acc1, 0, 0, 0);
            }
        }

        // epilogue: exp + grouped accumulation (overlaps the in-flight stage)
        const int col = colbase + ct * 16 + c16;
#pragma unroll
        for (int t = 0; t < 2; t++) {
            const f32x4 acv = t ? acc1 : acc0;
            const int rw0 = rowbase + t * 16 + q * 4;
#pragma unroll
            for (int r = 0; r < 4; r++) {
                const float val = __expf(acv[r] * INV_TEMP);
                tot[t][r] += val;
                pos[t][r] += (((trow[t] >> (8 * r)) & 255) == ctid[ct]) ? val : 0.f;
                if (wantdiag && col == rw0 + r) diag[col] = val;  // unique writer
            }
        }
        __syncthreads();   // next tile landed for all waves; reads of cur done
    }
#undef STAGE

    // Reduce across the 16 column-lanes sharing (q, r); one atomic per row.
#pragma unroll
    for (int t = 0; t < 2; t++)
#pragma unroll
        for (int r = 0; r < 4; r++) {
            float aS = tot[t][r], p = pos[t][r];
#pragma unroll
            for (int off = 1; off < 16; off <<= 1) {
                aS += __shfl_xor(aS, off);
                p  += __shfl_xor(p, off);
            }
            if (c16 == 0) {
                const int row = rowbase + t * 16 + q * 4 + r;
                atomicAdd(&Tot[row], aS);
                atomicAdd(mode ? &Pxx[row] : &Pxy[row], p);
            }
        }
}

// ------------------------------------------------ finalize (reads 32 KB only)
__global__ void finalize_kernel(const float* __restrict__ Tot, const float* __restrict__ Pxy,
                                const float* __restrict__ Pxx, const float* __restrict__ diag,
                                const int* __restrict__ tid, float* __restrict__ out) {
    __shared__ float num_s[TT], den_s[TT];
    __shared__ int cnt_s[TT];
    const int t = threadIdx.x;  // 256 threads
    num_s[t] = 0.f; den_s[t] = 0.f; cnt_s[t] = 0;
    __syncthreads();
    for (int i = t; i < NN; i += 256) {
        float tt_ = Tot[i], pxy = Pxy[i], pxx = Pxx[i];
        float num = pxy + 0.5f * (pxx - diag[i]);
        float den = tt_ - pxy - pxx;
        int tr = tid[i];
        atomicAdd(&num_s[tr], num);
        atomicAdd(&den_s[tr], den);
        atomicAdd(&cnt_s[tr], 1);
    }
    __syncthreads();
    float lt = 0.f, pr = 0.f;
    if (cnt_s[t] > 0) {
        lt = -logf(num_s[t] / (den_s[t] + num_s[t]));
        pr = 1.f;
    }
    for (int off = 32; off; off >>= 1) { lt += __shfl_down(lt, off); pr += __shfl_down(pr, off); }
    __shared__ float ls[4], ps[4];
    if ((t & 63) == 0) { ls[t >> 6] = lt; ps[t >> 6] = pr; }
    __syncthreads();
    if (t == 0) out[0] = (ls[0] + ls[1] + ls[2] + ls[3]) / (ps[0] + ps[1] + ps[2] + ps[3]);
}

// ------------------------------------------------ launch
extern "C" void kernel_launch(void* const* d_in, const int* in_sizes, int n_in,
                              void* d_out, int out_size, void* d_ws, size_t ws_size,
                              hipStream_t stream) {
    const float* x   = (const float*)d_in[0];
    const int*   tid = (const int*)d_in[1];
    const float* y   = (const float*)d_in[2];
    float* out = (float*)d_out;

    char* ws = (char*)d_ws;
    bf16x8* xfl = (bf16x8*)ws;                       // 1 MB frag-linear x
    bf16x8* yfl = (bf16x8*)(ws + (1u << 20));        // 8 MB frag-linear y
    float* acc  = (float*)(ws + 9u * (1u << 20));    // Tot,Pxy,Pxx,diag: 4*2048 f32
    float* Tot  = acc;
    float* Pxy  = acc + NN;
    float* Pxx  = acc + 2 * NN;
    float* diag = acc + 3 * NN;                      // fully rewritten by stats (mode 1)

    cvt_zero_kernel<<<2304, 256, 0, stream>>>(x, y, xfl, yfl, acc);
    stats_kernel<<<NROWBLK * (NCHUNK_XY + NCHUNK_XX), 256, 0, stream>>>(
        xfl, yfl, tid, Tot, Pxy, Pxx, diag);
    finalize_kernel<<<1, 256, 0, stream>>>(Tot, Pxy, Pxx, diag, tid, out);
}

// Round 15
// 109.236 us; speedup vs baseline: 2.5989x; 1.0388x over previous
//
#include <hip/hip_runtime.h>

// Problem constants (fixed by setup_inputs): N=2048, d=256, T=256, Q=64
#define NN   2048
#define DD   256
#define TT   256
#define NYC  16384           // T*Q flattened y columns
#define CHUNK_COLS 128
#define NCHUNK_XY 128        // 16384 / 128 cols per chunk
#define NCHUNK_XX 16         // 2048 / 128
#define NROWBLK   16         // 2048 / 128 rows per block

static constexpr float INV_TEMP = 1.0f / 0.3f;

typedef __bf16 bf16x8 __attribute__((ext_vector_type(8)));
typedef float  f32x4  __attribute__((ext_vector_type(4)));

// Frag-linear layout: for a matrix M[C][256] (bf16), fragment index
// j = (g*8 + ks)*64 + lane holds M[g*16 + (lane&15)][ks*32 + (lane>>4)*8 .. +7].
// A 16-col tile = 8 KB contiguous; staged to LDS it is already in ds_read
// fragment order (frag ks at lds ks*1024 + lane*16).

// ------------------------------------------------ convert + zero accumulators
__global__ void cvt_zero_kernel(const float* __restrict__ x, const float* __restrict__ y,
                                bf16x8* __restrict__ xfl, bf16x8* __restrict__ yfl,
                                float* __restrict__ acc /* 3*NN floats: Tot,Pxy,Pxx */) {
    const int tid0   = blockIdx.x * blockDim.x + threadIdx.x;
    const int stride = gridDim.x * blockDim.x;
    for (int j = tid0; j < 3 * NN; j += stride) acc[j] = 0.f;

    const int NXF = NN * DD / 8;          // 65536 x-fragments
    for (int j = tid0; j < NXF; j += stride) {
        const int gk  = j >> 6;           // g*8 + ks
        const int sub = j & 63;
        const int qq  = sub & 3;          // k-quad (lane>>4 in fragment space)
        const int cc  = (sub >> 2) & 15;  // col-within-16 (lane&15)
        const int col = ((gk >> 3) << 4) + cc;
        const int k0  = ((gk & 7) << 5) + (qq << 3);
        const float4* s = (const float4*)(x + (size_t)col * DD + k0);
        float4 v0 = s[0], v1 = s[1];
        bf16x8 o;
        o[0] = (__bf16)v0.x; o[1] = (__bf16)v0.y; o[2] = (__bf16)v0.z; o[3] = (__bf16)v0.w;
        o[4] = (__bf16)v1.x; o[5] = (__bf16)v1.y; o[6] = (__bf16)v1.z; o[7] = (__bf16)v1.w;
        xfl[(size_t)gk * 64 + qq * 16 + cc] = o;
    }
    const int NYF = NYC * DD / 8;         // 524288 y-fragments
    for (int j = tid0; j < NYF; j += stride) {
        const int gk  = j >> 6;
        const int sub = j & 63;
        const int qq  = sub & 3;
        const int cc  = (sub >> 2) & 15;
        const int col = ((gk >> 3) << 4) + cc;
        const int k0  = ((gk & 7) << 5) + (qq << 3);
        const float4* s = (const float4*)(y + (size_t)col * DD + k0);
        float4 v0 = s[0], v1 = s[1];
        bf16x8 o;
        o[0] = (__bf16)v0.x; o[1] = (__bf16)v0.y; o[2] = (__bf16)v0.z; o[3] = (__bf16)v0.w;
        o[4] = (__bf16)v1.x; o[5] = (__bf16)v1.y; o[6] = (__bf16)v1.z; o[7] = (__bf16)v1.w;
        yfl[(size_t)gk * 64 + qq * 16 + cc] = o;
    }
}

// ------------------------------------------------ stats (GEMM + exp + grouped sums)
// 2304 blocks (XCD-swizzled). 4 waves/block, wave owns 32 rows (t=2).
// R12 lesson: four structures (1-3 waves/SIMD, reg vs LDS staging) all land at
// ~40-50 us; issue accounting caps explainable time at ~15 us -> the other
// ~25 us is ALL waves stalled at the per-tile __syncthreads, whose vmcnt(0)
// drain exposes the full fetch latency (depth-1 prefetch < ~2000cyc latency).
// Fix (T3/T4): depth-3 stage (4 LDS bufs, 32 KB), counted `s_waitcnt vmcnt(4)`
// + RAW s_barrier each tile -- 2 newer stages stay in flight across barriers;
// the stage for tile ct was issued 3 tiles (~2400 cyc) earlier.
// Ledger note (R14 audit): diag global_stores also count in vmcnt; FIFO
// retire-oldest-first means the needed stage (always oldest) retires before
// any WAITV(N<=4) completes -- stores only cause benign over-waiting.
__global__ __launch_bounds__(256, 3) void stats_kernel(
        const bf16x8* __restrict__ xfl, const bf16x8* __restrict__ yfl,
        const int* __restrict__ tid,
        float* __restrict__ Tot, float* __restrict__ Pxy,
        float* __restrict__ Pxx, float* __restrict__ diag) {
    __shared__ __align__(16) char bstage[4][8192];   // 4 x (16 cols x 256 K bf16)

    const int id    = blockIdx.x;
    // XCD swizzle: id = hi*128 + bx*8 + lo; lo = XCD, chunk = lo + 8*hi.
    const int chunk = (id & 7) + ((id >> 7) << 3);   // 0..143
    const int bx    = (id >> 3) & 15;                // 0..15 row-block
    const int mode  = (chunk >= NCHUNK_XY);          // 0 = x@y^T, 1 = x@x^T
    const int colbase = (mode ? chunk - NCHUNK_XY : chunk) * CHUNK_COLS;
    const bf16x8* __restrict__ colfl = mode ? xfl : yfl;

    const int tix  = threadIdx.x;
    const int lane = tix & 63;
    const int w    = tix >> 6;
    const int c16  = lane & 15;
    const int q    = lane >> 4;
    const int rowbase = bx * 128 + w * 32;
    const int rowg    = rowbase >> 4;                // row16-group index

    const char* gbase = (const char*)colfl + ((size_t)(colbase >> 4)) * 8192 + tix * 16;
    const bool wantdiag = mode && (bx == (colbase >> 7));

    // Stage tile ct into LDS buffer (ct&3): 8 KB, 2 x 16 B per thread, linear.
#define STAGE(ct_)                                                                        \
    do {                                                                                  \
        const char* g_ = gbase + (size_t)(ct_) * 8192;                                    \
        __builtin_amdgcn_global_load_lds(                                                 \
            (const __attribute__((address_space(1))) void*)g_,                            \
            (__attribute__((address_space(3))) void*)&bstage[(ct_) & 3][tix * 16],        \
            16, 0, 0);                                                                    \
        __builtin_amdgcn_global_load_lds(                                                 \
            (const __attribute__((address_space(1))) void*)(g_ + 4096),                   \
            (__attribute__((address_space(3))) void*)&bstage[(ct_) & 3][4096 + tix * 16], \
            16, 0, 0);                                                                    \
    } while (0)
#define WAITV(n_) asm volatile("s_waitcnt vmcnt(" #n_ ")" ::: "memory")
#define BAR() __builtin_amdgcn_s_barrier()

    // Deep prefetch first -- everything below overlaps the stage latency.
    STAGE(0); STAGE(1); STAGE(2);

    // A fragments: 32 rows x K=256 resident in registers (64 VGPRs).
    bf16x8 a[2][8];
#pragma unroll
    for (int t = 0; t < 2; t++)
#pragma unroll
        for (int ks = 0; ks < 8; ks++)
            a[t][ks] = xfl[((size_t)(rowg + t) * 8 + ks) * 64 + lane];

    // Row track-ids packed 4x8-bit (tids < 256).
    int trow[2];
#pragma unroll
    for (int t = 0; t < 2; t++) {
        const int rb = rowbase + t * 16 + q * 4;
        trow[t] = tid[rb] | (tid[rb + 1] << 8) | (tid[rb + 2] << 16) | (tid[rb + 3] << 24);
    }

    // Column track-ids for all 8 tiles (static-indexed under full unroll).
    int ctid[8];
#pragma unroll
    for (int ct = 0; ct < 8; ct++) {
        const int col = colbase + ct * 16 + c16;
        ctid[ct] = mode ? tid[col] : (col & (TT - 1));
    }

    float tot[2][4] = {};
    float pos[2][4] = {};

    // COMPUTE(ct): MFMA from bstage[ct&3] + exp/grouped-sum epilogue.
#define COMPUTE(ct_)                                                                       \
    do {                                                                                   \
        const char* lbase = &bstage[(ct_) & 3][0];                                         \
        f32x4 acc0 = {0.f, 0.f, 0.f, 0.f};                                                 \
        f32x4 acc1 = {0.f, 0.f, 0.f, 0.f};                                                 \
        _Pragma("unroll")                                                                  \
        for (int h = 0; h < 2; h++) {                                                      \
            bf16x8 bf[4];                                                                  \
            _Pragma("unroll")                                                              \
            for (int k = 0; k < 4; k++)                                                    \
                bf[k] = *(const bf16x8*)(lbase + (h * 4 + k) * 1024 + lane * 16);          \
            _Pragma("unroll")                                                              \
            for (int k = 0; k < 4; k++) {                                                  \
                acc0 = __builtin_amdgcn_mfma_f32_16x16x32_bf16(a[0][h * 4 + k], bf[k],     \
                                                               acc0, 0, 0, 0);             \
                acc1 = __builtin_amdgcn_mfma_f32_16x16x32_bf16(a[1][h * 4 + k], bf[k],     \
                                                               acc1, 0, 0, 0);             \
            }                                                                              \
        }                                                                                  \
        const int col = colbase + (ct_) * 16 + c16;                                        \
        _Pragma("unroll")                                                                  \
        for (int t = 0; t < 2; t++) {                                                      \
            const f32x4 acv = t ? acc1 : acc0;                                             \
            const int rw0 = rowbase + t * 16 + q * 4;                                      \
            _Pragma("unroll")                                                              \
            for (int r = 0; r < 4; r++) {                                                  \
                const float val = __expf(acv[r] * INV_TEMP);                               \
                tot[t][r] += val;                                                          \
                pos[t][r] += (((trow[t] >> (8 * r)) & 255) == ctid[(ct_)]) ? val : 0.f;    \
                if (wantdiag && col == rw0 + r) diag[col] = val;                           \
            }                                                                              \
        }                                                                                  \
    } while (0)

    // Prologue wait: FIFO vmcnt -- everything but the 4 newest retired, so
    // stage 0 (oldest) and the A panel are in. Barrier publishes all slices.
    WAITV(4); BAR();

    STAGE(3); COMPUTE(0); WAITV(4); BAR();   // in flight after wait: stages 2,3
    STAGE(4); COMPUTE(1); WAITV(4); BAR();
    STAGE(5); COMPUTE(2); WAITV(4); BAR();
    STAGE(6); COMPUTE(3); WAITV(4); BAR();
    STAGE(7); COMPUTE(4); WAITV(4); BAR();
    COMPUTE(5); WAITV(2); BAR();
    COMPUTE(6); WAITV(0); BAR();
    COMPUTE(7);

#undef COMPUTE
#undef STAGE
#undef WAITV
#undef BAR

    // Reduce across the 16 column-lanes sharing (q, r); one atomic per row.
#pragma unroll
    for (int t = 0; t < 2; t++)
#pragma unroll
        for (int r = 0; r < 4; r++) {
            float aS = tot[t][r], p = pos[t][r];
#pragma unroll
            for (int off = 1; off < 16; off <<= 1) {
                aS += __shfl_xor(aS, off);
                p  += __shfl_xor(p, off);
            }
            if (c16 == 0) {
                const int row = rowbase + t * 16 + q * 4 + r;
                atomicAdd(&Tot[row], aS);
                atomicAdd(mode ? &Pxx[row] : &Pxy[row], p);
            }
        }
}

// ------------------------------------------------ finalize (reads 32 KB only)
__global__ void finalize_kernel(const float* __restrict__ Tot, const float* __restrict__ Pxy,
                                const float* __restrict__ Pxx, const float* __restrict__ diag,
                                const int* __restrict__ tid, float* __restrict__ out) {
    __shared__ float num_s[TT], den_s[TT];
    __shared__ int cnt_s[TT];
    const int t = threadIdx.x;  // 256 threads
    num_s[t] = 0.f; den_s[t] = 0.f; cnt_s[t] = 0;
    __syncthreads();
    for (int i = t; i < NN; i += 256) {
        float tt_ = Tot[i], pxy = Pxy[i], pxx = Pxx[i];
        float num = pxy + 0.5f * (pxx - diag[i]);
        float den = tt_ - pxy - pxx;
        int tr = tid[i];
        atomicAdd(&num_s[tr], num);
        atomicAdd(&den_s[tr], den);
        atomicAdd(&cnt_s[tr], 1);
    }
    __syncthreads();
    float lt = 0.f, pr = 0.f;
    if (cnt_s[t] > 0) {
        lt = -logf(num_s[t] / (den_s[t] + num_s[t]));
        pr = 1.f;
    }
    for (int off = 32; off; off >>= 1) { lt += __shfl_down(lt, off); pr += __shfl_down(pr, off); }
    __shared__ float ls[4], ps[4];
    if ((t & 63) == 0) { ls[t >> 6] = lt; ps[t >> 6] = pr; }
    __syncthreads();
    if (t == 0) out[0] = (ls[0] + ls[1] + ls[2] + ls[3]) / (ps[0] + ps[1] + ps[2] + ps[3]);
}

// ------------------------------------------------ launch
extern "C" void kernel_launch(void* const* d_in, const int* in_sizes, int n_in,
                              void* d_out, int out_size, void* d_ws, size_t ws_size,
                              hipStream_t stream) {
    const float* x   = (const float*)d_in[0];
    const int*   tid = (const int*)d_in[1];
    const float* y   = (const float*)d_in[2];
    float* out = (float*)d_out;

    char* ws = (char*)d_ws;
    bf16x8* xfl = (bf16x8*)ws;                       // 1 MB frag-linear x
    bf16x8* yfl = (bf16x8*)(ws + (1u << 20));        // 8 MB frag-linear y
    float* acc  = (float*)(ws + 9u * (1u << 20));    // Tot,Pxy,Pxx,diag: 4*2048 f32
    float* Tot  = acc;
    float* Pxy  = acc + NN;
    float* Pxx  = acc + 2 * NN;
    float* diag = acc + 3 * NN;                      // fully rewritten by stats (mode 1)

    cvt_zero_kernel<<<2304, 256, 0, stream>>>(x, y, xfl, yfl, acc);
    stats_kernel<<<NROWBLK * (NCHUNK_XY + NCHUNK_XX), 256, 0, stream>>>(
        xfl, yfl, tid, Tot, Pxy, Pxx, diag);
    finalize_kernel<<<1, 256, 0, stream>>>(Tot, Pxy, Pxx, diag, tid, out);
}